// Round 1
// 266.870 us; speedup vs baseline: 1.0058x; 1.0058x over previous
//
#include <hip/hip_runtime.h>

// B=8, N=1024, C=1024, H=16, HD=64
// R14: GEMMs ported to the 256x256 8-wave 4-phase schedule (T2 LDS swizzle +
//      T3 phase split + T4 counted vmcnt(8) + T5 setprio). 128KB dynamic LDS,
//      BK=64, dist-2 staging into phase-dead regions of the current buffer,
//      XCD-bijective block swizzle. Attention (R9) and convert unchanged.

typedef __attribute__((ext_vector_type(8))) short bf16x8;
typedef __attribute__((ext_vector_type(4))) short bf16x4;
typedef __attribute__((ext_vector_type(4))) float f32x4;

__device__ __forceinline__ short f2bf(float f) {
    union { float f; unsigned u; } x;
    x.f = f;
    unsigned r = x.u + 0x7fffu + ((x.u >> 16) & 1u);  // RNE
    return (short)(r >> 16);
}

__device__ __forceinline__ void load_lds16(const void* g, void* l) {
    __builtin_amdgcn_global_load_lds((const __attribute__((address_space(1))) unsigned*)g,
                                     (__attribute__((address_space(3))) unsigned*)l,
                                     16, 0, 0);
}

// ---------------- merged fp32 -> bf16 convert ----------------
__global__ __launch_bounds__(256) void convert_all(const float* __restrict__ x,
                                                   const float* __restrict__ wqkv,
                                                   const float* __restrict__ wproj,
                                                   short* __restrict__ xb,
                                                   short* __restrict__ wqkvb,
                                                   short* __restrict__ wprojb) {
    int i = blockIdx.x * 256 + threadIdx.x;
    const float* src;
    short* dst;
    int j;
    if (i < 2097152)      { src = x;     dst = xb;     j = i; }
    else if (i < 2883584) { src = wqkv;  dst = wqkvb;  j = i - 2097152; }
    else                  { src = wproj; dst = wprojb; j = i - 2883584; }
    float4 v = *(const float4*)(src + j * 4);
    unsigned lo = (unsigned short)f2bf(v.x) | ((unsigned)(unsigned short)f2bf(v.y) << 16);
    unsigned hi = (unsigned short)f2bf(v.z) | ((unsigned)(unsigned short)f2bf(v.w) << 16);
    uint2 p; p.x = lo; p.y = hi;
    *(uint2*)(dst + j * 4) = p;
}

// ---------------- 256x256 8-wave 4-phase GEMM template ----------------
// EPI=0: QKV epilogue (scatter to q/k/vt, bf16).  EPI=1: proj epilogue (f32+bias).
// NTX = N-tiles (N/256). Grid = 32*NTX blocks of 512 threads, 128KB dyn LDS.
template<int EPI, int NTX>
__global__ __launch_bounds__(512, 2) void gemm256(const short* __restrict__ A,
                                                  const short* __restrict__ Bt,
                                                  short* __restrict__ q,
                                                  short* __restrict__ kk,
                                                  short* __restrict__ vt,
                                                  const float* __restrict__ bias,
                                                  float* __restrict__ out) {
    extern __shared__ short lds[];
    short* const As = lds;            // [2][256][64]
    short* const Bs = lds + 32768;    // [2][256][64]
    const int K = 1024;

    // XCD-bijective swizzle: 8 XCDs, CHUNK consecutive tiles per XCD.
    constexpr int CHUNK = NTX * 4;    // (32*NTX)/8
    const int bid = blockIdx.x;
    const int tile = (bid & 7) * CHUNK + (bid >> 3);
    const int m0 = (tile / NTX) * 256;
    const int n0 = (tile % NTX) * 256;

    const int t = threadIdx.x;
    const int w = t >> 6, lane = t & 63, quad = lane >> 4, l16 = lane & 15;
    const int wm = (w >> 2) * 128, wn = (w & 3) * 64;   // wave tile 128x64
    const int sw = l16 & 7;                              // row&7 for all frag rows

    // staging: round r covers rows r*64 + srow; source col pre-swizzled so the
    // linear global_load_lds dest yields LDS[row][slot] = G[row][slot ^ (row&7)]
    const int srow = t >> 3;                             // 0..63
    const int scol = ((t & 7) ^ (srow & 7)) * 8;
    const short* Ag = A  + (m0 + srow) * K + scol;
    const short* Bg = Bt + (n0 + srow) * K + scol;
    short* const Asw = As + (w * 8) * 64;                // wave-uniform dest base
    short* const Bsw = Bs + (w * 8) * 64;

    f32x4 acc[8][4];
    #pragma unroll
    for (int mi = 0; mi < 8; ++mi)
        #pragma unroll
        for (int ni = 0; ni < 4; ++ni) acc[mi][ni] = (f32x4){0.f, 0.f, 0.f, 0.f};

    bf16x8 af[4][2], bf[4][2];

#define STG_A(kt_, d_, r_) load_lds16(Ag + (r_) * 64 * K + (kt_) * 64, Asw + (d_) * 16384 + (r_) * 4096)
#define STG_B(kt_, d_, r_) load_lds16(Bg + (r_) * 64 * K + (kt_) * 64, Bsw + (d_) * 16384 + (r_) * 4096)

    // prologue: kt0 -> buf0, kt1 -> buf1 (16 loads); keep kt1's 8 in flight
    STG_A(0, 0, 0); STG_A(0, 0, 1); STG_A(0, 0, 2); STG_A(0, 0, 3);
    STG_B(0, 0, 0); STG_B(0, 0, 1); STG_B(0, 0, 2); STG_B(0, 0, 3);
    STG_A(1, 1, 0); STG_A(1, 1, 1); STG_A(1, 1, 2); STG_A(1, 1, 3);
    STG_B(1, 1, 0); STG_B(1, 1, 1); STG_B(1, 1, 2); STG_B(1, 1, 3);
    asm volatile("s_waitcnt vmcnt(8)" ::: "memory");
    asm volatile("s_barrier" ::: "memory");

    #pragma unroll
    for (int kt = 0; kt < 16; ++kt) {
        const int d = kt & 1;
        const short* Ar = As + d * 16384;
        const short* Br = Bs + d * 16384;

        // ---- P0: read A[qm0] + B[qn0]; MFMA mi0-3 x ni0-1 ----
        #pragma unroll
        for (int mi = 0; mi < 4; ++mi)
            #pragma unroll
            for (int c = 0; c < 2; ++c)
                af[mi][c] = *(const bf16x8*)(Ar + (wm + mi * 16 + l16) * 64 + (((quad + 4 * c) ^ sw) * 8));
        #pragma unroll
        for (int ni = 0; ni < 2; ++ni)
            #pragma unroll
            for (int c = 0; c < 2; ++c)
                bf[ni][c] = *(const bf16x8*)(Br + (wn + ni * 16 + l16) * 64 + (((quad + 4 * c) ^ sw) * 8));
        asm volatile("s_barrier" ::: "memory");
        asm volatile("s_waitcnt lgkmcnt(0)" ::: "memory");
        __builtin_amdgcn_sched_barrier(0);
        __builtin_amdgcn_s_setprio(1);
        #pragma unroll
        for (int mi = 0; mi < 4; ++mi)
            #pragma unroll
            for (int ni = 0; ni < 2; ++ni) {
                acc[mi][ni] = __builtin_amdgcn_mfma_f32_16x16x32_bf16(af[mi][0], bf[ni][0], acc[mi][ni], 0, 0, 0);
                acc[mi][ni] = __builtin_amdgcn_mfma_f32_16x16x32_bf16(af[mi][1], bf[ni][1], acc[mi][ni], 0, 0, 0);
            }
        __builtin_amdgcn_s_setprio(0);
        asm volatile("s_barrier" ::: "memory");

        // ---- P1: read B[qn1]; stage A(kt+2) r0,r2 (A rows {0-63,128-191} dead after P0);
        //          MFMA mi0-3 x ni2-3 ----
        #pragma unroll
        for (int ni = 2; ni < 4; ++ni)
            #pragma unroll
            for (int c = 0; c < 2; ++c)
                bf[ni][c] = *(const bf16x8*)(Br + (wn + ni * 16 + l16) * 64 + (((quad + 4 * c) ^ sw) * 8));
        if (kt < 14) { STG_A(kt + 2, d, 0); STG_A(kt + 2, d, 2); }
        asm volatile("s_barrier" ::: "memory");
        asm volatile("s_waitcnt lgkmcnt(0)" ::: "memory");
        __builtin_amdgcn_sched_barrier(0);
        __builtin_amdgcn_s_setprio(1);
        #pragma unroll
        for (int mi = 0; mi < 4; ++mi)
            #pragma unroll
            for (int ni = 2; ni < 4; ++ni) {
                acc[mi][ni] = __builtin_amdgcn_mfma_f32_16x16x32_bf16(af[mi][0], bf[ni][0], acc[mi][ni], 0, 0, 0);
                acc[mi][ni] = __builtin_amdgcn_mfma_f32_16x16x32_bf16(af[mi][1], bf[ni][1], acc[mi][ni], 0, 0, 0);
            }
        __builtin_amdgcn_s_setprio(0);
        asm volatile("s_barrier" ::: "memory");

        // ---- P2: read A[qm1]; stage B(kt+2) r0,r1 (all B dead after P1);
        //          MFMA mi4-7 x ni0-1 (bf[0..1] still live) ----
        #pragma unroll
        for (int mi = 0; mi < 4; ++mi)
            #pragma unroll
            for (int c = 0; c < 2; ++c)
                af[mi][c] = *(const bf16x8*)(Ar + (wm + 64 + mi * 16 + l16) * 64 + (((quad + 4 * c) ^ sw) * 8));
        if (kt < 14) { STG_B(kt + 2, d, 0); STG_B(kt + 2, d, 1); }
        asm volatile("s_barrier" ::: "memory");
        asm volatile("s_waitcnt lgkmcnt(0)" ::: "memory");
        __builtin_amdgcn_sched_barrier(0);
        __builtin_amdgcn_s_setprio(1);
        #pragma unroll
        for (int mi = 0; mi < 4; ++mi)
            #pragma unroll
            for (int ni = 0; ni < 2; ++ni) {
                acc[mi + 4][ni] = __builtin_amdgcn_mfma_f32_16x16x32_bf16(af[mi][0], bf[ni][0], acc[mi + 4][ni], 0, 0, 0);
                acc[mi + 4][ni] = __builtin_amdgcn_mfma_f32_16x16x32_bf16(af[mi][1], bf[ni][1], acc[mi + 4][ni], 0, 0, 0);
            }
        __builtin_amdgcn_s_setprio(0);
        asm volatile("s_barrier" ::: "memory");

        // ---- P3: MFMA mi4-7 x ni2-3 (regs only); stage B r2,r3 + A r1,r3
        //          (A rows {64-127,192-255} dead after P2); counted vmcnt;
        //          K-tile boundary barrier ----
        __builtin_amdgcn_s_setprio(1);
        #pragma unroll
        for (int mi = 0; mi < 4; ++mi)
            #pragma unroll
            for (int ni = 2; ni < 4; ++ni) {
                acc[mi + 4][ni] = __builtin_amdgcn_mfma_f32_16x16x32_bf16(af[mi][0], bf[ni][0], acc[mi + 4][ni], 0, 0, 0);
                acc[mi + 4][ni] = __builtin_amdgcn_mfma_f32_16x16x32_bf16(af[mi][1], bf[ni][1], acc[mi + 4][ni], 0, 0, 0);
            }
        __builtin_amdgcn_s_setprio(0);
        if (kt < 14) { STG_B(kt + 2, d, 2); STG_B(kt + 2, d, 3); STG_A(kt + 2, d, 1); STG_A(kt + 2, d, 3); }
        if (kt < 14)       asm volatile("s_waitcnt vmcnt(8)" ::: "memory");  // kt+1 landed, kt+2 in flight
        else if (kt == 14) asm volatile("s_waitcnt vmcnt(0)" ::: "memory");  // drain for last tile
        asm volatile("s_barrier" ::: "memory");
    }
#undef STG_A
#undef STG_B

    // ---- epilogue ----
    if (EPI == 0) {
        const float QS = 0.125f * 1.44269504088896f;
        #pragma unroll
        for (int ni = 0; ni < 4; ++ni) {
            int col = n0 + wn + ni * 16 + l16;
            int sect = col >> 10;
            int c = col & 1023;
            int h = c >> 6, dd = c & 63;
            #pragma unroll
            for (int mi = 0; mi < 8; ++mi) {
                #pragma unroll
                for (int r = 0; r < 4; ++r) {
                    int m = m0 + wm + mi * 16 + quad * 4 + r;
                    int b = m >> 10, i = m & 1023;
                    float v = acc[mi][ni][r];
                    if (sect == 0)      q[((b * 16 + h) * 1024 + i) * 64 + dd] = f2bf(v * QS);
                    else if (sect == 1) kk[((b * 16 + h) * 1024 + i) * 64 + dd] = f2bf(v);
                    else                vt[((b * 16 + h) * 64 + dd) * 1024 + i] = f2bf(v);
                }
            }
        }
    } else {
        #pragma unroll
        for (int ni = 0; ni < 4; ++ni) {
            int col = n0 + wn + ni * 16 + l16;
            float bv = bias[col];
            #pragma unroll
            for (int mi = 0; mi < 8; ++mi) {
                #pragma unroll
                for (int r = 0; r < 4; ++r) {
                    int m = m0 + wm + mi * 16 + quad * 4 + r;
                    out[m * 1024 + col] = acc[mi][ni][r] + bv;
                }
            }
        }
    }
}

// ---------------- Flash attention: dbuf K/V, 1 barrier/jt, register P (R9) ----------------
__global__ __launch_bounds__(256) void attn_kernel(const short* __restrict__ q,
                                                   const short* __restrict__ k,
                                                   const short* __restrict__ vt,
                                                   short* __restrict__ ao) {
    __shared__ alignas(16) short Ks[2][64][72];
    __shared__ alignas(16) short Vs[2][64][72];

    const int bh = blockIdx.y, qt = blockIdx.x;
    const int t = threadIdx.x, w = t >> 6, lane = t & 63, quad = lane >> 4, l16 = lane & 15;
    const short* qg = q  + (bh * 1024 + qt * 128) * 64;
    const short* kg = k  + bh * 65536;
    const short* vg = vt + bh * 65536;

    bf16x8 qf[2][2];
    for (int mi = 0; mi < 2; ++mi) {
        const short* qr = qg + (w * 32 + mi * 16 + l16) * 64;
        qf[mi][0] = *(const bf16x8*)(qr + quad * 8);
        qf[mi][1] = *(const bf16x8*)(qr + 32 + quad * 8);
    }

    const int r0 = t >> 3,          c80 = (t & 7) * 8;
    const int r1 = (t + 256) >> 3,  c81 = c80;

    float rs[2] = {0.f, 0.f};
    f32x4 oaccT[2][4];
    for (int mi = 0; mi < 2; ++mi)
        for (int dt = 0; dt < 4; ++dt) oaccT[mi][dt] = (f32x4){0.f, 0.f, 0.f, 0.f};

    {
        float4 a = *(const float4*)&kg[r0 * 64 + c80];
        float4 b = *(const float4*)&kg[r1 * 64 + c81];
        float4 c = *(const float4*)&vg[r0 * 1024 + c80];
        float4 d = *(const float4*)&vg[r1 * 1024 + c81];
        *(float4*)&Ks[0][r0][c80] = a;  *(float4*)&Ks[0][r1][c81] = b;
        *(float4*)&Vs[0][r0][c80] = c;  *(float4*)&Vs[0][r1][c81] = d;
    }

    for (int jt = 0; jt < 16; ++jt) {
        const int cur = jt & 1;
        asm volatile("s_waitcnt lgkmcnt(0)" ::: "memory");
        asm volatile("s_barrier" ::: "memory");

        float4 kr0, kr1, vr0, vr1;
        if (jt < 15) {
            int jn = jt + 1;
            kr0 = *(const float4*)&kg[(jn * 64 + r0) * 64 + c80];
            kr1 = *(const float4*)&kg[(jn * 64 + r1) * 64 + c81];
            vr0 = *(const float4*)&vg[r0 * 1024 + jn * 64 + c80];
            vr1 = *(const float4*)&vg[r1 * 1024 + jn * 64 + c81];
        }

        for (int js = 0; js < 4; ++js) {
            bf16x8 kf0 = *(const bf16x8*)&Ks[cur][js * 16 + l16][quad * 8];
            bf16x8 kf1 = *(const bf16x8*)&Ks[cur][js * 16 + l16][32 + quad * 8];
            bf16x4 vtf[4];
            for (int dt = 0; dt < 4; ++dt)
                vtf[dt] = *(const bf16x4*)&Vs[cur][dt * 16 + l16][js * 16 + quad * 4];
            for (int mi = 0; mi < 2; ++mi) {
                f32x4 s = (f32x4){0.f, 0.f, 0.f, 0.f};
                s = __builtin_amdgcn_mfma_f32_16x16x32_bf16(kf0, qf[mi][0], s, 0, 0, 0);
                s = __builtin_amdgcn_mfma_f32_16x16x32_bf16(kf1, qf[mi][1], s, 0, 0, 0);
                bf16x4 pfrag;
                for (int r = 0; r < 4; ++r) {
                    float p = __builtin_amdgcn_exp2f(s[r]);
                    rs[mi] += p;
                    pfrag[r] = f2bf(p);
                }
                for (int dt = 0; dt < 4; ++dt)
                    oaccT[mi][dt] = __builtin_amdgcn_mfma_f32_16x16x16bf16_1k(
                        vtf[dt], pfrag, oaccT[mi][dt], 0, 0, 0);
            }
        }

        if (jt < 15) {
            const int nxt = cur ^ 1;
            *(float4*)&Ks[nxt][r0][c80] = kr0;  *(float4*)&Ks[nxt][r1][c81] = kr1;
            *(float4*)&Vs[nxt][r0][c80] = vr0;  *(float4*)&Vs[nxt][r1][c81] = vr1;
        }
    }

    for (int mi = 0; mi < 2; ++mi) {
        rs[mi] += __shfl_xor(rs[mi], 16, 64);
        rs[mi] += __shfl_xor(rs[mi], 32, 64);
    }

    const int b = bh >> 4, h = bh & 15;
    for (int mi = 0; mi < 2; ++mi) {
        float inv = 1.0f / rs[mi];
        int i = qt * 128 + w * 32 + mi * 16 + l16;
        short* aor = ao + (b * 1024 + i) * 1024 + h * 64;
        for (int dt = 0; dt < 4; ++dt) {
            bf16x4 o4;
            for (int r = 0; r < 4; ++r) o4[r] = f2bf(oaccT[mi][dt][r] * inv);
            *(bf16x4*)(aor + dt * 16 + quad * 4) = o4;
        }
    }
}

extern "C" void kernel_launch(void* const* d_in, const int* in_sizes, int n_in,
                              void* d_out, int out_size, void* d_ws, size_t ws_size,
                              hipStream_t stream) {
    const float* x      = (const float*)d_in[0];
    const float* w_qkv  = (const float*)d_in[1];
    const float* w_proj = (const float*)d_in[2];
    const float* b_proj = (const float*)d_in[3];
    float* out = (float*)d_out;

    char* ws = (char*)d_ws;
    short* xb     = (short*)(ws);
    short* wqkvb  = (short*)(ws + 16777216);
    short* wprojb = (short*)(ws + 23068672);
    short* qb     = (short*)(ws + 25165824);
    short* kb     = (short*)(ws + 41943040);
    short* vtb    = (short*)(ws + 58720256);
    short* aob    = (short*)(ws + 75497472);

    static bool s_init = false;
    if (!s_init) {
        hipFuncSetAttribute(reinterpret_cast<const void*>(&gemm256<0, 12>),
                            hipFuncAttributeMaxDynamicSharedMemorySize, 131072);
        hipFuncSetAttribute(reinterpret_cast<const void*>(&gemm256<1, 4>),
                            hipFuncAttributeMaxDynamicSharedMemorySize, 131072);
        s_init = true;
    }

    convert_all<<<12288, 256, 0, stream>>>(x, w_qkv, w_proj, xb, wqkvb, wprojb);
    gemm256<0, 12><<<384, 512, 131072, stream>>>(xb, wqkvb, qb, kb, vtb, nullptr, nullptr);
    attn_kernel<<<dim3(8, 128), 256, 0, stream>>>(qb, kb, vtb, aob);
    gemm256<1, 4><<<128, 512, 131072, stream>>>(aob, wprojb, nullptr, nullptr, nullptr, b_proj, out);
}

// Round 2
// 256.531 us; speedup vs baseline: 1.0464x; 1.0403x over previous
//
#include <hip/hip_runtime.h>

// B=8, N=1024, C=1024, H=16, HD=64
// R15: GEMMs: boundary-staged double-buffer with minimal sync graph:
//      per K-tile = [reads A0+B, lgkm0, MFMA] [reads A1, lgkm0, MFMA]
//      [barrier] [stage kt+2 -> current buf] [vmcnt(NLD) counted] [barrier].
//      2 barriers/tile (was 9), counted vmcnt with a full-tile slack.
//      Perfect grid packing: QKV 256x192 tiles -> 512 blocks (2 exact rounds),
//      proj 128x256 -> 256 blocks (1 exact round). Conflict-free XOR swizzle
//      via pre-swizzled global source (linear global_load_lds dest) retained.
//      Attention (R9) and convert unchanged.

typedef __attribute__((ext_vector_type(8))) short bf16x8;
typedef __attribute__((ext_vector_type(4))) short bf16x4;
typedef __attribute__((ext_vector_type(4))) float f32x4;

__device__ __forceinline__ short f2bf(float f) {
    union { float f; unsigned u; } x;
    x.f = f;
    unsigned r = x.u + 0x7fffu + ((x.u >> 16) & 1u);  // RNE
    return (short)(r >> 16);
}

__device__ __forceinline__ void load_lds16(const void* g, void* l) {
    __builtin_amdgcn_global_load_lds((const __attribute__((address_space(1))) unsigned*)g,
                                     (__attribute__((address_space(3))) unsigned*)l,
                                     16, 0, 0);
}

// ---------------- merged fp32 -> bf16 convert ----------------
__global__ __launch_bounds__(256) void convert_all(const float* __restrict__ x,
                                                   const float* __restrict__ wqkv,
                                                   const float* __restrict__ wproj,
                                                   short* __restrict__ xb,
                                                   short* __restrict__ wqkvb,
                                                   short* __restrict__ wprojb) {
    int i = blockIdx.x * 256 + threadIdx.x;
    const float* src;
    short* dst;
    int j;
    if (i < 2097152)      { src = x;     dst = xb;     j = i; }
    else if (i < 2883584) { src = wqkv;  dst = wqkvb;  j = i - 2097152; }
    else                  { src = wproj; dst = wprojb; j = i - 2883584; }
    float4 v = *(const float4*)(src + j * 4);
    unsigned lo = (unsigned short)f2bf(v.x) | ((unsigned)(unsigned short)f2bf(v.y) << 16);
    unsigned hi = (unsigned short)f2bf(v.z) | ((unsigned)(unsigned short)f2bf(v.w) << 16);
    uint2 p; p.x = lo; p.y = hi;
    *(uint2*)(dst + j * 4) = p;
}

// ---------------- 2-sub-phase boundary-staged GEMM template ----------------
// 8 waves (2M x 4N), BK=64, double-buffered LDS, dist-2 boundary staging.
// EPI=0: QKV scatter epilogue. EPI=1: proj f32+bias epilogue.
template<int EPI, int BM, int BN, int NTX>
__global__ __launch_bounds__(512, 2) void gemm2p(const short* __restrict__ A,
                                                 const short* __restrict__ Bt,
                                                 short* __restrict__ q,
                                                 short* __restrict__ kk,
                                                 short* __restrict__ vt,
                                                 const float* __restrict__ bias,
                                                 float* __restrict__ out) {
    extern __shared__ short lds[];
    constexpr int AU = BM / 64, BU = BN / 64, NLD = AU + BU;  // stage units/tile
    constexpr int WM = BM / 2, WN = BN / 4;                   // wave tile
    constexpr int MF = WM / 16, NF = WN / 16, MF2 = MF / 2;
    constexpr int NWG = (8192 / BM) * NTX;
    constexpr int CHUNK = NWG / 8;
    short* const As = lds;                  // [2][BM][64]
    short* const Bs = lds + 2 * BM * 64;    // [2][BN][64]
    const int K = 1024;

    const int bid = blockIdx.x;
    const int tile = (bid & 7) * CHUNK + (bid >> 3);   // XCD-bijective (NWG%8==0)
    const int m0 = (tile / NTX) * BM;
    const int n0 = (tile % NTX) * BN;

    const int t = threadIdx.x;
    const int w = t >> 6, lane = t & 63, quad = lane >> 4, l16 = lane & 15;
    const int wm = (w >> 2) * WM, wn = (w & 3) * WN;
    const int sw = l16 & 7;

    // staging: unit r covers rows r*64+srow; source col pre-swizzled so linear
    // global_load_lds dest yields LDS[row][slot] = G[row][slot ^ (row&7)]
    const int srow = t >> 3;                           // 0..63
    const int scol = ((t & 7) ^ (srow & 7)) * 8;
    const short* Ag = A  + (m0 + srow) * K + scol;
    const short* Bg = Bt + (n0 + srow) * K + scol;
    short* const Asw = As + (w * 8) * 64;              // wave-uniform dest base
    short* const Bsw = Bs + (w * 8) * 64;

    f32x4 acc[MF][NF];
    #pragma unroll
    for (int mi = 0; mi < MF; ++mi)
        #pragma unroll
        for (int ni = 0; ni < NF; ++ni) acc[mi][ni] = (f32x4){0.f, 0.f, 0.f, 0.f};

    bf16x8 af[MF2][2], bf[NF][2];

#define STG_A(kt_, r_) load_lds16(Ag + (r_) * 64 * K + (kt_) * 64, Asw + ((kt_) & 1) * (BM * 64) + (r_) * 4096)
#define STG_B(kt_, r_) load_lds16(Bg + (r_) * 64 * K + (kt_) * 64, Bsw + ((kt_) & 1) * (BN * 64) + (r_) * 4096)
#define WAIT_VM_NLD() do { if constexpr (NLD == 7) asm volatile("s_waitcnt vmcnt(7)" ::: "memory"); \
                           else                    asm volatile("s_waitcnt vmcnt(6)" ::: "memory"); } while (0)

    // prologue: stage kt0 and kt1; wait kt0 landed (kt1 stays in flight)
    #pragma unroll
    for (int r = 0; r < AU; ++r) STG_A(0, r);
    #pragma unroll
    for (int r = 0; r < BU; ++r) STG_B(0, r);
    #pragma unroll
    for (int r = 0; r < AU; ++r) STG_A(1, r);
    #pragma unroll
    for (int r = 0; r < BU; ++r) STG_B(1, r);
    WAIT_VM_NLD();
    asm volatile("s_barrier" ::: "memory");

    #pragma unroll
    for (int kt = 0; kt < 16; ++kt) {
        const short* Ar = As + (kt & 1) * (BM * 64);
        const short* Br = Bs + (kt & 1) * (BN * 64);

        // ---- sub-phase 0: A-half0 + all B; MFMA mi[0..MF2) x all ni ----
        #pragma unroll
        for (int mi = 0; mi < MF2; ++mi)
            #pragma unroll
            for (int c = 0; c < 2; ++c)
                af[mi][c] = *(const bf16x8*)(Ar + (wm + mi * 16 + l16) * 64 + (((quad + 4 * c) ^ sw) * 8));
        #pragma unroll
        for (int ni = 0; ni < NF; ++ni)
            #pragma unroll
            for (int c = 0; c < 2; ++c)
                bf[ni][c] = *(const bf16x8*)(Br + (wn + ni * 16 + l16) * 64 + (((quad + 4 * c) ^ sw) * 8));
        asm volatile("s_waitcnt lgkmcnt(0)" ::: "memory");
        __builtin_amdgcn_sched_barrier(0);
        __builtin_amdgcn_s_setprio(1);
        #pragma unroll
        for (int mi = 0; mi < MF2; ++mi)
            #pragma unroll
            for (int ni = 0; ni < NF; ++ni) {
                acc[mi][ni] = __builtin_amdgcn_mfma_f32_16x16x32_bf16(af[mi][0], bf[ni][0], acc[mi][ni], 0, 0, 0);
                acc[mi][ni] = __builtin_amdgcn_mfma_f32_16x16x32_bf16(af[mi][1], bf[ni][1], acc[mi][ni], 0, 0, 0);
            }
        __builtin_amdgcn_s_setprio(0);

        // ---- sub-phase 1: A-half1; MFMA mi[MF2..MF) x all ni ----
        #pragma unroll
        for (int mi = 0; mi < MF2; ++mi)
            #pragma unroll
            for (int c = 0; c < 2; ++c)
                af[mi][c] = *(const bf16x8*)(Ar + (wm + (MF2 + mi) * 16 + l16) * 64 + (((quad + 4 * c) ^ sw) * 8));
        asm volatile("s_waitcnt lgkmcnt(0)" ::: "memory");
        __builtin_amdgcn_sched_barrier(0);
        __builtin_amdgcn_s_setprio(1);
        #pragma unroll
        for (int mi = 0; mi < MF2; ++mi)
            #pragma unroll
            for (int ni = 0; ni < NF; ++ni) {
                acc[MF2 + mi][ni] = __builtin_amdgcn_mfma_f32_16x16x32_bf16(af[mi][0], bf[ni][0], acc[MF2 + mi][ni], 0, 0, 0);
                acc[MF2 + mi][ni] = __builtin_amdgcn_mfma_f32_16x16x32_bf16(af[mi][1], bf[ni][1], acc[MF2 + mi][ni], 0, 0, 0);
            }
        __builtin_amdgcn_s_setprio(0);

        // ---- boundary: all waves' reads retired -> stage kt+2 into current
        //      buf; counted vmcnt (kt+1's loads, issued a full tile ago) ----
        if (kt < 15) {
            asm volatile("s_barrier" ::: "memory");          // reads of buf retired
            if (kt < 14) {
                #pragma unroll
                for (int r = 0; r < AU; ++r) STG_A(kt + 2, r);
                #pragma unroll
                for (int r = 0; r < BU; ++r) STG_B(kt + 2, r);
                WAIT_VM_NLD();                               // kt+1 landed, kt+2 in flight
            } else {
                asm volatile("s_waitcnt vmcnt(0)" ::: "memory");  // drain: kt15 landed
            }
            asm volatile("s_barrier" ::: "memory");          // next tile readable
        }
    }
#undef STG_A
#undef STG_B
#undef WAIT_VM_NLD

    // ---- epilogue ----
    if (EPI == 0) {
        const float QS = 0.125f * 1.44269504088896f;
        #pragma unroll
        for (int ni = 0; ni < NF; ++ni) {
            int col = n0 + wn + ni * 16 + l16;
            int sect = col >> 10;
            int c = col & 1023;
            int h = c >> 6, dd = c & 63;
            #pragma unroll
            for (int mi = 0; mi < MF; ++mi) {
                #pragma unroll
                for (int r = 0; r < 4; ++r) {
                    int m = m0 + wm + mi * 16 + quad * 4 + r;
                    int b = m >> 10, i = m & 1023;
                    float v = acc[mi][ni][r];
                    if (sect == 0)      q[((b * 16 + h) * 1024 + i) * 64 + dd] = f2bf(v * QS);
                    else if (sect == 1) kk[((b * 16 + h) * 1024 + i) * 64 + dd] = f2bf(v);
                    else                vt[((b * 16 + h) * 64 + dd) * 1024 + i] = f2bf(v);
                }
            }
        }
    } else {
        #pragma unroll
        for (int ni = 0; ni < NF; ++ni) {
            int col = n0 + wn + ni * 16 + l16;
            float bv = bias[col];
            #pragma unroll
            for (int mi = 0; mi < MF; ++mi) {
                #pragma unroll
                for (int r = 0; r < 4; ++r) {
                    int m = m0 + wm + mi * 16 + quad * 4 + r;
                    out[m * 1024 + col] = acc[mi][ni][r] + bv;
                }
            }
        }
    }
}

// ---------------- Flash attention: dbuf K/V, 1 barrier/jt, register P (R9) ----------------
__global__ __launch_bounds__(256) void attn_kernel(const short* __restrict__ q,
                                                   const short* __restrict__ k,
                                                   const short* __restrict__ vt,
                                                   short* __restrict__ ao) {
    __shared__ alignas(16) short Ks[2][64][72];
    __shared__ alignas(16) short Vs[2][64][72];

    const int bh = blockIdx.y, qt = blockIdx.x;
    const int t = threadIdx.x, w = t >> 6, lane = t & 63, quad = lane >> 4, l16 = lane & 15;
    const short* qg = q  + (bh * 1024 + qt * 128) * 64;
    const short* kg = k  + bh * 65536;
    const short* vg = vt + bh * 65536;

    bf16x8 qf[2][2];
    for (int mi = 0; mi < 2; ++mi) {
        const short* qr = qg + (w * 32 + mi * 16 + l16) * 64;
        qf[mi][0] = *(const bf16x8*)(qr + quad * 8);
        qf[mi][1] = *(const bf16x8*)(qr + 32 + quad * 8);
    }

    const int r0 = t >> 3,          c80 = (t & 7) * 8;
    const int r1 = (t + 256) >> 3,  c81 = c80;

    float rs[2] = {0.f, 0.f};
    f32x4 oaccT[2][4];
    for (int mi = 0; mi < 2; ++mi)
        for (int dt = 0; dt < 4; ++dt) oaccT[mi][dt] = (f32x4){0.f, 0.f, 0.f, 0.f};

    {
        float4 a = *(const float4*)&kg[r0 * 64 + c80];
        float4 b = *(const float4*)&kg[r1 * 64 + c81];
        float4 c = *(const float4*)&vg[r0 * 1024 + c80];
        float4 d = *(const float4*)&vg[r1 * 1024 + c81];
        *(float4*)&Ks[0][r0][c80] = a;  *(float4*)&Ks[0][r1][c81] = b;
        *(float4*)&Vs[0][r0][c80] = c;  *(float4*)&Vs[0][r1][c81] = d;
    }

    for (int jt = 0; jt < 16; ++jt) {
        const int cur = jt & 1;
        asm volatile("s_waitcnt lgkmcnt(0)" ::: "memory");
        asm volatile("s_barrier" ::: "memory");

        float4 kr0, kr1, vr0, vr1;
        if (jt < 15) {
            int jn = jt + 1;
            kr0 = *(const float4*)&kg[(jn * 64 + r0) * 64 + c80];
            kr1 = *(const float4*)&kg[(jn * 64 + r1) * 64 + c81];
            vr0 = *(const float4*)&vg[r0 * 1024 + jn * 64 + c80];
            vr1 = *(const float4*)&vg[r1 * 1024 + jn * 64 + c81];
        }

        for (int js = 0; js < 4; ++js) {
            bf16x8 kf0 = *(const bf16x8*)&Ks[cur][js * 16 + l16][quad * 8];
            bf16x8 kf1 = *(const bf16x8*)&Ks[cur][js * 16 + l16][32 + quad * 8];
            bf16x4 vtf[4];
            for (int dt = 0; dt < 4; ++dt)
                vtf[dt] = *(const bf16x4*)&Vs[cur][dt * 16 + l16][js * 16 + quad * 4];
            for (int mi = 0; mi < 2; ++mi) {
                f32x4 s = (f32x4){0.f, 0.f, 0.f, 0.f};
                s = __builtin_amdgcn_mfma_f32_16x16x32_bf16(kf0, qf[mi][0], s, 0, 0, 0);
                s = __builtin_amdgcn_mfma_f32_16x16x32_bf16(kf1, qf[mi][1], s, 0, 0, 0);
                bf16x4 pfrag;
                for (int r = 0; r < 4; ++r) {
                    float p = __builtin_amdgcn_exp2f(s[r]);
                    rs[mi] += p;
                    pfrag[r] = f2bf(p);
                }
                for (int dt = 0; dt < 4; ++dt)
                    oaccT[mi][dt] = __builtin_amdgcn_mfma_f32_16x16x16bf16_1k(
                        vtf[dt], pfrag, oaccT[mi][dt], 0, 0, 0);
            }
        }

        if (jt < 15) {
            const int nxt = cur ^ 1;
            *(float4*)&Ks[nxt][r0][c80] = kr0;  *(float4*)&Ks[nxt][r1][c81] = kr1;
            *(float4*)&Vs[nxt][r0][c80] = vr0;  *(float4*)&Vs[nxt][r1][c81] = vr1;
        }
    }

    for (int mi = 0; mi < 2; ++mi) {
        rs[mi] += __shfl_xor(rs[mi], 16, 64);
        rs[mi] += __shfl_xor(rs[mi], 32, 64);
    }

    const int b = bh >> 4, h = bh & 15;
    for (int mi = 0; mi < 2; ++mi) {
        float inv = 1.0f / rs[mi];
        int i = qt * 128 + w * 32 + mi * 16 + l16;
        short* aor = ao + (b * 1024 + i) * 1024 + h * 64;
        for (int dt = 0; dt < 4; ++dt) {
            bf16x4 o4;
            for (int r = 0; r < 4; ++r) o4[r] = f2bf(oaccT[mi][dt][r] * inv);
            *(bf16x4*)(aor + dt * 16 + quad * 4) = o4;
        }
    }
}

extern "C" void kernel_launch(void* const* d_in, const int* in_sizes, int n_in,
                              void* d_out, int out_size, void* d_ws, size_t ws_size,
                              hipStream_t stream) {
    const float* x      = (const float*)d_in[0];
    const float* w_qkv  = (const float*)d_in[1];
    const float* w_proj = (const float*)d_in[2];
    const float* b_proj = (const float*)d_in[3];
    float* out = (float*)d_out;

    char* ws = (char*)d_ws;
    short* xb     = (short*)(ws);
    short* wqkvb  = (short*)(ws + 16777216);
    short* wprojb = (short*)(ws + 23068672);
    short* qb     = (short*)(ws + 25165824);
    short* kb     = (short*)(ws + 41943040);
    short* vtb    = (short*)(ws + 58720256);
    short* aob    = (short*)(ws + 75497472);

    static bool s_init = false;
    if (!s_init) {
        hipFuncSetAttribute(reinterpret_cast<const void*>(&gemm2p<0, 256, 192, 16>),
                            hipFuncAttributeMaxDynamicSharedMemorySize, 114688);
        hipFuncSetAttribute(reinterpret_cast<const void*>(&gemm2p<1, 128, 256, 4>),
                            hipFuncAttributeMaxDynamicSharedMemorySize, 98304);
        s_init = true;
    }

    convert_all<<<12288, 256, 0, stream>>>(x, w_qkv, w_proj, xb, wqkvb, wprojb);
    // QKV: M=8192,N=3072 -> 32x16 tiles of 256x192 = 512 blocks (2 exact rounds)
    gemm2p<0, 256, 192, 16><<<512, 512, 114688, stream>>>(xb, wqkvb, qb, kb, vtb, nullptr, nullptr);
    attn_kernel<<<dim3(8, 128), 256, 0, stream>>>(qb, kb, vtb, aob);
    // proj: M=8192,N=1024 -> 64x4 tiles of 128x256 = 256 blocks (1 exact round)
    gemm2p<1, 128, 256, 4><<<256, 512, 98304, stream>>>(aob, wprojb, nullptr, nullptr, nullptr, b_proj, out);
}

// Round 3
// 256.179 us; speedup vs baseline: 1.0478x; 1.0014x over previous
//
#include <hip/hip_runtime.h>

// B=8, N=1024, C=1024, H=16, HD=64
// R16: faithful m201-style 4-phase-per-K-tile schedule for both GEMMs:
//      per phase {ds_read subtile; trickle 2-3 global_load_lds; barrier;
//      lgkmcnt(0); sched_barrier(0); setprio(1); MFMA quadrant; setprio(0);
//      barrier}; ONE counted vmcnt(2) per K-tile (vmcnt(0) only at kt=14).
//      Stage schedule derived from slot liveness, >=3-phase lead per load.
//      QKV 256x192 (512 blk = 2 exact rounds), proj 128x256 (256 blk = 1 round).
//      Attention (R9) and convert unchanged.

typedef __attribute__((ext_vector_type(8))) short bf16x8;
typedef __attribute__((ext_vector_type(4))) short bf16x4;
typedef __attribute__((ext_vector_type(4))) float f32x4;

__device__ __forceinline__ short f2bf(float f) {
    union { float f; unsigned u; } x;
    x.f = f;
    unsigned r = x.u + 0x7fffu + ((x.u >> 16) & 1u);  // RNE
    return (short)(r >> 16);
}

__device__ __forceinline__ void load_lds16(const void* g, void* l) {
    __builtin_amdgcn_global_load_lds((const __attribute__((address_space(1))) unsigned*)g,
                                     (__attribute__((address_space(3))) unsigned*)l,
                                     16, 0, 0);
}

// ---------------- merged fp32 -> bf16 convert ----------------
__global__ __launch_bounds__(256) void convert_all(const float* __restrict__ x,
                                                   const float* __restrict__ wqkv,
                                                   const float* __restrict__ wproj,
                                                   short* __restrict__ xb,
                                                   short* __restrict__ wqkvb,
                                                   short* __restrict__ wprojb) {
    int i = blockIdx.x * 256 + threadIdx.x;
    const float* src;
    short* dst;
    int j;
    if (i < 2097152)      { src = x;     dst = xb;     j = i; }
    else if (i < 2883584) { src = wqkv;  dst = wqkvb;  j = i - 2097152; }
    else                  { src = wproj; dst = wprojb; j = i - 2883584; }
    float4 v = *(const float4*)(src + j * 4);
    unsigned lo = (unsigned short)f2bf(v.x) | ((unsigned)(unsigned short)f2bf(v.y) << 16);
    unsigned hi = (unsigned short)f2bf(v.z) | ((unsigned)(unsigned short)f2bf(v.w) << 16);
    uint2 p; p.x = lo; p.y = hi;
    *(uint2*)(dst + j * 4) = p;
}

// ---------------- 4-phase trickle-staged GEMM (m201 discipline) ----------------
// 8 waves (2M x 4N), BK=64, dbuf LDS, per-phase stage trickle, 1 vmcnt/tile.
// EPI=0: QKV scatter epilogue (BM=256,BN=192). EPI=1: proj (BM=128,BN=256).
template<int EPI, int BM, int BN, int NTX>
__global__ __launch_bounds__(512, 2) void gemm8p(const short* __restrict__ A,
                                                 const short* __restrict__ Bt,
                                                 short* __restrict__ q,
                                                 short* __restrict__ kk,
                                                 short* __restrict__ vt,
                                                 const float* __restrict__ bias,
                                                 float* __restrict__ out) {
    extern __shared__ short lds[];
    constexpr int WM = BM / 2, WN = BN / 4;
    constexpr int MF = WM / 16, NF = WN / 16, MH = MF / 2, HM = WM / 2;
    constexpr int NWG = (8192 / BM) * NTX;
    constexpr int CHUNK = NWG / 8;
    short* const As = lds;                   // [2][BM][64]
    short* const Bs = lds + 2 * BM * 64;     // [2][BN][64]
    const int K = 1024;

    const int bid = blockIdx.x;
    const int tile = (bid & 7) * CHUNK + (bid >> 3);   // XCD-bijective (NWG%8==0)
    const int m0 = (tile / NTX) * BM;
    const int n0 = (tile % NTX) * BN;

    const int t = threadIdx.x;
    const int w = t >> 6, lane = t & 63, quad = lane >> 4, l16 = lane & 15;
    const int wm = (w >> 2) * WM, wn = (w & 3) * WN;
    const int sw = l16 & 7;

    // staging: unit u covers rows u*64+srow; source col pre-swizzled so the
    // linear global_load_lds dest yields LDS[row][slot] = G[row][slot ^ (row&7)]
    const int srow = t >> 3;                            // 0..63
    const int scol = ((t & 7) ^ (srow & 7)) * 8;
    const short* Ag = A  + (m0 + srow) * K + scol;
    const short* Bg = Bt + (n0 + srow) * K + scol;
    const int w8 = w * 8 * 64;                          // wave slice in unit (shorts)

    f32x4 acc[MF][NF];
    #pragma unroll
    for (int mi = 0; mi < MF; ++mi)
        #pragma unroll
        for (int ni = 0; ni < NF; ++ni) acc[mi][ni] = (f32x4){0.f, 0.f, 0.f, 0.f};

    bf16x8 af[MH][2], bf[NF][2];

#define STG_A(kt_, u_) load_lds16(Ag + (u_) * (64 * 1024) + (kt_) * 64, \
                                  As + ((kt_) & 1) * (BM * 64) + (u_) * 4096 + w8)
#define STG_B(kt_, u_) load_lds16(Bg + (u_) * (64 * 1024) + (kt_) * 64, \
                                  Bs + ((kt_) & 1) * (BN * 64) + (u_) * 4096 + w8)

    // ---- prologue: tile0 fully + tile1's out-of-band A units; vmcnt(2) ----
    if (EPI == 0) {
        STG_A(0, 0); STG_A(0, 1); STG_A(0, 2); STG_A(0, 3);
        STG_B(0, 0); STG_B(0, 1); STG_B(0, 2);
        STG_A(1, 0); STG_A(1, 2);
    } else {
        STG_B(0, 0); STG_B(0, 1); STG_B(0, 2); STG_B(0, 3);
        STG_A(0, 0); STG_A(0, 1);
        STG_A(1, 0); STG_A(1, 1);
    }
    asm volatile("s_waitcnt vmcnt(2)" ::: "memory");
    asm volatile("s_barrier" ::: "memory");

    auto ktbody = [&](int KT, bool ST1, bool ST2, bool LASTW) __attribute__((always_inline)) {
        const short* Ar = As + (KT & 1) * (BM * 64);
        const short* Br = Bs + (KT & 1) * (BN * 64);

        // ---- P0: read af(mh0) + bf(ni 0..1); stage trickle; MFMA Q(0,0) ----
        #pragma unroll
        for (int mi = 0; mi < MH; ++mi)
            #pragma unroll
            for (int c = 0; c < 2; ++c)
                af[mi][c] = *(const bf16x8*)(Ar + (wm + mi * 16 + l16) * 64 + (((quad + 4 * c) ^ sw) * 8));
        #pragma unroll
        for (int ni = 0; ni < 2; ++ni)
            #pragma unroll
            for (int c = 0; c < 2; ++c)
                bf[ni][c] = *(const bf16x8*)(Br + (wn + ni * 16 + l16) * 64 + (((quad + 4 * c) ^ sw) * 8));
        if (EPI == 0) { if (ST1) { STG_A(KT + 1, 1); STG_A(KT + 1, 3); } }
        else          { if (ST1) { STG_B(KT + 1, 0); STG_B(KT + 1, 1); } }
        asm volatile("s_barrier" ::: "memory");
        asm volatile("s_waitcnt lgkmcnt(0)" ::: "memory");
        __builtin_amdgcn_sched_barrier(0);
        __builtin_amdgcn_s_setprio(1);
        #pragma unroll
        for (int mi = 0; mi < MH; ++mi)
            #pragma unroll
            for (int ni = 0; ni < 2; ++ni) {
                acc[mi][ni] = __builtin_amdgcn_mfma_f32_16x16x32_bf16(af[mi][0], bf[ni][0], acc[mi][ni], 0, 0, 0);
                acc[mi][ni] = __builtin_amdgcn_mfma_f32_16x16x32_bf16(af[mi][1], bf[ni][1], acc[mi][ni], 0, 0, 0);
            }
        __builtin_amdgcn_s_setprio(0);
        asm volatile("s_barrier" ::: "memory");

        // ---- P1: read bf(ni 2..NF-1); stage trickle; MFMA Q(0,1) ----
        #pragma unroll
        for (int ni = 2; ni < NF; ++ni)
            #pragma unroll
            for (int c = 0; c < 2; ++c)
                bf[ni][c] = *(const bf16x8*)(Br + (wn + ni * 16 + l16) * 64 + (((quad + 4 * c) ^ sw) * 8));
        if (EPI == 0) { if (ST1) { STG_B(KT + 1, 0); STG_B(KT + 1, 1); STG_B(KT + 1, 2); } }
        else          { if (ST1) { STG_B(KT + 1, 2); STG_B(KT + 1, 3); } }
        asm volatile("s_barrier" ::: "memory");
        asm volatile("s_waitcnt lgkmcnt(0)" ::: "memory");
        __builtin_amdgcn_sched_barrier(0);
        __builtin_amdgcn_s_setprio(1);
        #pragma unroll
        for (int mi = 0; mi < MH; ++mi)
            #pragma unroll
            for (int ni = 2; ni < NF; ++ni) {
                acc[mi][ni] = __builtin_amdgcn_mfma_f32_16x16x32_bf16(af[mi][0], bf[ni][0], acc[mi][ni], 0, 0, 0);
                acc[mi][ni] = __builtin_amdgcn_mfma_f32_16x16x32_bf16(af[mi][1], bf[ni][1], acc[mi][ni], 0, 0, 0);
            }
        __builtin_amdgcn_s_setprio(0);
        asm volatile("s_barrier" ::: "memory");

        // ---- P2: read af(mh1); stage trickle; MFMA Q(1,0) ----
        #pragma unroll
        for (int mi = 0; mi < MH; ++mi)
            #pragma unroll
            for (int c = 0; c < 2; ++c)
                af[mi][c] = *(const bf16x8*)(Ar + (wm + HM + mi * 16 + l16) * 64 + (((quad + 4 * c) ^ sw) * 8));
        if (EPI == 0) { if (ST2) { STG_A(KT + 2, 0); STG_A(KT + 2, 2); } }
        asm volatile("s_barrier" ::: "memory");
        asm volatile("s_waitcnt lgkmcnt(0)" ::: "memory");
        __builtin_amdgcn_sched_barrier(0);
        __builtin_amdgcn_s_setprio(1);
        #pragma unroll
        for (int mi = 0; mi < MH; ++mi)
            #pragma unroll
            for (int ni = 0; ni < 2; ++ni) {
                acc[MH + mi][ni] = __builtin_amdgcn_mfma_f32_16x16x32_bf16(af[mi][0], bf[ni][0], acc[MH + mi][ni], 0, 0, 0);
                acc[MH + mi][ni] = __builtin_amdgcn_mfma_f32_16x16x32_bf16(af[mi][1], bf[ni][1], acc[MH + mi][ni], 0, 0, 0);
            }
        __builtin_amdgcn_s_setprio(0);
        asm volatile("s_barrier" ::: "memory");

        // ---- P3: no reads; stage trickle (proj); MFMA Q(1,1); vmcnt; bar ----
        if (EPI == 1) { if (ST2) { STG_A(KT + 2, 0); STG_A(KT + 2, 1); } }
        asm volatile("s_barrier" ::: "memory");
        asm volatile("s_waitcnt lgkmcnt(0)" ::: "memory");
        __builtin_amdgcn_sched_barrier(0);
        __builtin_amdgcn_s_setprio(1);
        #pragma unroll
        for (int mi = 0; mi < MH; ++mi)
            #pragma unroll
            for (int ni = 2; ni < NF; ++ni) {
                acc[MH + mi][ni] = __builtin_amdgcn_mfma_f32_16x16x32_bf16(af[mi][0], bf[ni][0], acc[MH + mi][ni], 0, 0, 0);
                acc[MH + mi][ni] = __builtin_amdgcn_mfma_f32_16x16x32_bf16(af[mi][1], bf[ni][1], acc[MH + mi][ni], 0, 0, 0);
            }
        __builtin_amdgcn_s_setprio(0);
        if (LASTW) asm volatile("s_waitcnt vmcnt(0)" ::: "memory");
        else       asm volatile("s_waitcnt vmcnt(2)" ::: "memory");
        asm volatile("s_barrier" ::: "memory");
    };

    #pragma unroll 1
    for (int j = 0; j < 8; ++j) {
        ktbody(2 * j,     true,  j < 7, j == 7);
        ktbody(2 * j + 1, j < 7, j < 7, false);
    }
#undef STG_A
#undef STG_B

    // ---- epilogue ----
    if (EPI == 0) {
        const float QS = 0.125f * 1.44269504088896f;
        #pragma unroll
        for (int ni = 0; ni < NF; ++ni) {
            int col = n0 + wn + ni * 16 + l16;
            int sect = col >> 10;
            int c = col & 1023;
            int h = c >> 6, dd = c & 63;
            #pragma unroll
            for (int mi = 0; mi < MF; ++mi) {
                #pragma unroll
                for (int r = 0; r < 4; ++r) {
                    int m = m0 + wm + mi * 16 + quad * 4 + r;
                    int b = m >> 10, i = m & 1023;
                    float v = acc[mi][ni][r];
                    if (sect == 0)      q[((b * 16 + h) * 1024 + i) * 64 + dd] = f2bf(v * QS);
                    else if (sect == 1) kk[((b * 16 + h) * 1024 + i) * 64 + dd] = f2bf(v);
                    else                vt[((b * 16 + h) * 64 + dd) * 1024 + i] = f2bf(v);
                }
            }
        }
    } else {
        #pragma unroll
        for (int ni = 0; ni < NF; ++ni) {
            int col = n0 + wn + ni * 16 + l16;
            float bv = bias[col];
            #pragma unroll
            for (int mi = 0; mi < MF; ++mi) {
                #pragma unroll
                for (int r = 0; r < 4; ++r) {
                    int m = m0 + wm + mi * 16 + quad * 4 + r;
                    out[m * 1024 + col] = acc[mi][ni][r] + bv;
                }
            }
        }
    }
}

// ---------------- Flash attention: dbuf K/V, 1 barrier/jt, register P (R9) ----------------
__global__ __launch_bounds__(256) void attn_kernel(const short* __restrict__ q,
                                                   const short* __restrict__ k,
                                                   const short* __restrict__ vt,
                                                   short* __restrict__ ao) {
    __shared__ alignas(16) short Ks[2][64][72];
    __shared__ alignas(16) short Vs[2][64][72];

    const int bh = blockIdx.y, qt = blockIdx.x;
    const int t = threadIdx.x, w = t >> 6, lane = t & 63, quad = lane >> 4, l16 = lane & 15;
    const short* qg = q  + (bh * 1024 + qt * 128) * 64;
    const short* kg = k  + bh * 65536;
    const short* vg = vt + bh * 65536;

    bf16x8 qf[2][2];
    for (int mi = 0; mi < 2; ++mi) {
        const short* qr = qg + (w * 32 + mi * 16 + l16) * 64;
        qf[mi][0] = *(const bf16x8*)(qr + quad * 8);
        qf[mi][1] = *(const bf16x8*)(qr + 32 + quad * 8);
    }

    const int r0 = t >> 3,          c80 = (t & 7) * 8;
    const int r1 = (t + 256) >> 3,  c81 = c80;

    float rs[2] = {0.f, 0.f};
    f32x4 oaccT[2][4];
    for (int mi = 0; mi < 2; ++mi)
        for (int dt = 0; dt < 4; ++dt) oaccT[mi][dt] = (f32x4){0.f, 0.f, 0.f, 0.f};

    {
        float4 a = *(const float4*)&kg[r0 * 64 + c80];
        float4 b = *(const float4*)&kg[r1 * 64 + c81];
        float4 c = *(const float4*)&vg[r0 * 1024 + c80];
        float4 d = *(const float4*)&vg[r1 * 1024 + c81];
        *(float4*)&Ks[0][r0][c80] = a;  *(float4*)&Ks[0][r1][c81] = b;
        *(float4*)&Vs[0][r0][c80] = c;  *(float4*)&Vs[0][r1][c81] = d;
    }

    for (int jt = 0; jt < 16; ++jt) {
        const int cur = jt & 1;
        asm volatile("s_waitcnt lgkmcnt(0)" ::: "memory");
        asm volatile("s_barrier" ::: "memory");

        float4 kr0, kr1, vr0, vr1;
        if (jt < 15) {
            int jn = jt + 1;
            kr0 = *(const float4*)&kg[(jn * 64 + r0) * 64 + c80];
            kr1 = *(const float4*)&kg[(jn * 64 + r1) * 64 + c81];
            vr0 = *(const float4*)&vg[r0 * 1024 + jn * 64 + c80];
            vr1 = *(const float4*)&vg[r1 * 1024 + jn * 64 + c81];
        }

        for (int js = 0; js < 4; ++js) {
            bf16x8 kf0 = *(const bf16x8*)&Ks[cur][js * 16 + l16][quad * 8];
            bf16x8 kf1 = *(const bf16x8*)&Ks[cur][js * 16 + l16][32 + quad * 8];
            bf16x4 vtf[4];
            for (int dt = 0; dt < 4; ++dt)
                vtf[dt] = *(const bf16x4*)&Vs[cur][dt * 16 + l16][js * 16 + quad * 4];
            for (int mi = 0; mi < 2; ++mi) {
                f32x4 s = (f32x4){0.f, 0.f, 0.f, 0.f};
                s = __builtin_amdgcn_mfma_f32_16x16x32_bf16(kf0, qf[mi][0], s, 0, 0, 0);
                s = __builtin_amdgcn_mfma_f32_16x16x32_bf16(kf1, qf[mi][1], s, 0, 0, 0);
                bf16x4 pfrag;
                for (int r = 0; r < 4; ++r) {
                    float p = __builtin_amdgcn_exp2f(s[r]);
                    rs[mi] += p;
                    pfrag[r] = f2bf(p);
                }
                for (int dt = 0; dt < 4; ++dt)
                    oaccT[mi][dt] = __builtin_amdgcn_mfma_f32_16x16x16bf16_1k(
                        vtf[dt], pfrag, oaccT[mi][dt], 0, 0, 0);
            }
        }

        if (jt < 15) {
            const int nxt = cur ^ 1;
            *(float4*)&Ks[nxt][r0][c80] = kr0;  *(float4*)&Ks[nxt][r1][c81] = kr1;
            *(float4*)&Vs[nxt][r0][c80] = vr0;  *(float4*)&Vs[nxt][r1][c81] = vr1;
        }
    }

    for (int mi = 0; mi < 2; ++mi) {
        rs[mi] += __shfl_xor(rs[mi], 16, 64);
        rs[mi] += __shfl_xor(rs[mi], 32, 64);
    }

    const int b = bh >> 4, h = bh & 15;
    for (int mi = 0; mi < 2; ++mi) {
        float inv = 1.0f / rs[mi];
        int i = qt * 128 + w * 32 + mi * 16 + l16;
        short* aor = ao + (b * 1024 + i) * 1024 + h * 64;
        for (int dt = 0; dt < 4; ++dt) {
            bf16x4 o4;
            for (int r = 0; r < 4; ++r) o4[r] = f2bf(oaccT[mi][dt][r] * inv);
            *(bf16x4*)(aor + dt * 16 + quad * 4) = o4;
        }
    }
}

extern "C" void kernel_launch(void* const* d_in, const int* in_sizes, int n_in,
                              void* d_out, int out_size, void* d_ws, size_t ws_size,
                              hipStream_t stream) {
    const float* x      = (const float*)d_in[0];
    const float* w_qkv  = (const float*)d_in[1];
    const float* w_proj = (const float*)d_in[2];
    const float* b_proj = (const float*)d_in[3];
    float* out = (float*)d_out;

    char* ws = (char*)d_ws;
    short* xb     = (short*)(ws);
    short* wqkvb  = (short*)(ws + 16777216);
    short* wprojb = (short*)(ws + 23068672);
    short* qb     = (short*)(ws + 25165824);
    short* kb     = (short*)(ws + 41943040);
    short* vtb    = (short*)(ws + 58720256);
    short* aob    = (short*)(ws + 75497472);

    static bool s_init = false;
    if (!s_init) {
        hipFuncSetAttribute(reinterpret_cast<const void*>(&gemm8p<0, 256, 192, 16>),
                            hipFuncAttributeMaxDynamicSharedMemorySize, 114688);
        hipFuncSetAttribute(reinterpret_cast<const void*>(&gemm8p<1, 128, 256, 4>),
                            hipFuncAttributeMaxDynamicSharedMemorySize, 98304);
        s_init = true;
    }

    convert_all<<<12288, 256, 0, stream>>>(x, w_qkv, w_proj, xb, wqkvb, wprojb);
    // QKV: M=8192,N=3072 -> 32x16 tiles of 256x192 = 512 blocks (2 exact rounds)
    gemm8p<0, 256, 192, 16><<<512, 512, 114688, stream>>>(xb, wqkvb, qb, kb, vtb, nullptr, nullptr);
    attn_kernel<<<dim3(8, 128), 256, 0, stream>>>(qb, kb, vtb, aob);
    // proj: M=8192,N=1024 -> 64x4 tiles of 128x256 = 256 blocks (1 exact round)
    gemm8p<1, 128, 256, 4><<<256, 512, 98304, stream>>>(aob, wprojb, nullptr, nullptr, nullptr, b_proj, out);
}

// Round 4
// 239.984 us; speedup vs baseline: 1.1185x; 1.0675x over previous
//
#include <hip/hip_runtime.h>

// B=8, N=1024, C=1024, H=16, HD=64
// R17: GEMMs rewritten compiler-friendly m97-style: NO manual asm sync at all
//      (R14-R16 post-mortem: every hand-asm schedule pinned at ~21% MfmaUtil
//      = the m141 "order-pinning defeats compiler scheduling -> 510 TF" trap).
//      128x128 tile, 4 waves, BK=64, single-buffer 32KB static LDS, plain
//      __syncthreads(), __launch_bounds__(256,3) -> 3 blocks/CU for
//      inter-block async overlap (m97/m114 mechanism, measured 37% util).
//      Pre-swizzled-source staging + XOR read (0 conflicts) and XCD swizzle
//      retained. QKV: 1536 blocks = 2 exact rounds of 768; proj: 512 blocks
//      all-resident. Attention (R9) and convert unchanged.

typedef __attribute__((ext_vector_type(8))) short bf16x8;
typedef __attribute__((ext_vector_type(4))) short bf16x4;
typedef __attribute__((ext_vector_type(4))) float f32x4;

__device__ __forceinline__ short f2bf(float f) {
    union { float f; unsigned u; } x;
    x.f = f;
    unsigned r = x.u + 0x7fffu + ((x.u >> 16) & 1u);  // RNE
    return (short)(r >> 16);
}

__device__ __forceinline__ void load_lds16(const void* g, void* l) {
    __builtin_amdgcn_global_load_lds((const __attribute__((address_space(1))) unsigned*)g,
                                     (__attribute__((address_space(3))) unsigned*)l,
                                     16, 0, 0);
}

// ---------------- merged fp32 -> bf16 convert ----------------
__global__ __launch_bounds__(256) void convert_all(const float* __restrict__ x,
                                                   const float* __restrict__ wqkv,
                                                   const float* __restrict__ wproj,
                                                   short* __restrict__ xb,
                                                   short* __restrict__ wqkvb,
                                                   short* __restrict__ wprojb) {
    int i = blockIdx.x * 256 + threadIdx.x;
    const float* src;
    short* dst;
    int j;
    if (i < 2097152)      { src = x;     dst = xb;     j = i; }
    else if (i < 2883584) { src = wqkv;  dst = wqkvb;  j = i - 2097152; }
    else                  { src = wproj; dst = wprojb; j = i - 2883584; }
    float4 v = *(const float4*)(src + j * 4);
    unsigned lo = (unsigned short)f2bf(v.x) | ((unsigned)(unsigned short)f2bf(v.y) << 16);
    unsigned hi = (unsigned short)f2bf(v.z) | ((unsigned)(unsigned short)f2bf(v.w) << 16);
    uint2 p; p.x = lo; p.y = hi;
    *(uint2*)(dst + j * 4) = p;
}

// ---------------- m97-style 128x128 GEMM, compiler-scheduled ----------------
// 4 waves (2x2 of 64x64), BK=64, single 32KB LDS buffer, 2 barriers/K-tile,
// no manual waitcnt (compiler emits drains for __syncthreads semantics).
// EPI=0: QKV scatter epilogue. EPI=1: proj f32+bias epilogue.
template<int EPI, int NTX>
__global__ __launch_bounds__(256, 3) void gemm97(const short* __restrict__ A,
                                                 const short* __restrict__ Bt,
                                                 short* __restrict__ q,
                                                 short* __restrict__ kk,
                                                 short* __restrict__ vt,
                                                 const float* __restrict__ bias,
                                                 float* __restrict__ out) {
    __shared__ alignas(16) short As[128][64];
    __shared__ alignas(16) short Bs[128][64];
    const int K = 1024;
    constexpr int NWG = 64 * NTX;          // (8192/128) * NTX
    constexpr int CHUNK = NWG / 8;

    const int bid = blockIdx.x;
    const int tile = (bid & 7) * CHUNK + (bid >> 3);   // XCD-bijective (NWG%8==0)
    const int m0 = (tile / NTX) * 128;
    const int n0 = (tile % NTX) * 128;

    const int t = threadIdx.x;
    const int w = t >> 6, lane = t & 63, quad = lane >> 4, l16 = lane & 15;
    const int wm = (w >> 1) * 64, wn = (w & 1) * 64;
    const int sw = l16 & 7;

    // staging: round r covers rows r*32 + srow; source col pre-swizzled so the
    // linear global_load_lds dest yields LDS[row][slot] = G[row][slot ^ (row&7)]
    const int srow = t >> 3;                            // 0..31
    const int scol = ((t & 7) ^ (srow & 7)) * 8;
    const short* Ag = A  + (m0 + srow) * K + scol;
    const short* Bg = Bt + (n0 + srow) * K + scol;
    short* const Asw = &As[w * 8][0];                   // wave-uniform dest base
    short* const Bsw = &Bs[w * 8][0];

    f32x4 acc[4][4];
    #pragma unroll
    for (int mi = 0; mi < 4; ++mi)
        #pragma unroll
        for (int ni = 0; ni < 4; ++ni) acc[mi][ni] = (f32x4){0.f, 0.f, 0.f, 0.f};

    #pragma unroll 1
    for (int kt = 0; kt < 16; ++kt) {
        __syncthreads();   // everyone done reading previous tile
        #pragma unroll
        for (int r = 0; r < 4; ++r)
            load_lds16(Ag + r * 32 * K + kt * 64, Asw + r * 32 * 64);
        #pragma unroll
        for (int r = 0; r < 4; ++r)
            load_lds16(Bg + r * 32 * K + kt * 64, Bsw + r * 32 * 64);
        __syncthreads();   // compiler inserts vmcnt(0): DMA landed

        bf16x8 af[4][2], bf[4][2];
        #pragma unroll
        for (int mi = 0; mi < 4; ++mi)
            #pragma unroll
            for (int c = 0; c < 2; ++c)
                af[mi][c] = *(const bf16x8*)&As[wm + mi * 16 + l16][((quad + 4 * c) ^ sw) * 8];
        #pragma unroll
        for (int ni = 0; ni < 4; ++ni)
            #pragma unroll
            for (int c = 0; c < 2; ++c)
                bf[ni][c] = *(const bf16x8*)&Bs[wn + ni * 16 + l16][((quad + 4 * c) ^ sw) * 8];
        #pragma unroll
        for (int mi = 0; mi < 4; ++mi)
            #pragma unroll
            for (int ni = 0; ni < 4; ++ni) {
                acc[mi][ni] = __builtin_amdgcn_mfma_f32_16x16x32_bf16(af[mi][0], bf[ni][0], acc[mi][ni], 0, 0, 0);
                acc[mi][ni] = __builtin_amdgcn_mfma_f32_16x16x32_bf16(af[mi][1], bf[ni][1], acc[mi][ni], 0, 0, 0);
            }
    }

    // ---- epilogue ----
    if (EPI == 0) {
        const float QS = 0.125f * 1.44269504088896f;
        #pragma unroll
        for (int ni = 0; ni < 4; ++ni) {
            int col = n0 + wn + ni * 16 + l16;
            int sect = col >> 10;
            int c = col & 1023;
            int h = c >> 6, dd = c & 63;
            #pragma unroll
            for (int mi = 0; mi < 4; ++mi) {
                #pragma unroll
                for (int r = 0; r < 4; ++r) {
                    int m = m0 + wm + mi * 16 + quad * 4 + r;
                    int b = m >> 10, i = m & 1023;
                    float v = acc[mi][ni][r];
                    if (sect == 0)      q[((b * 16 + h) * 1024 + i) * 64 + dd] = f2bf(v * QS);
                    else if (sect == 1) kk[((b * 16 + h) * 1024 + i) * 64 + dd] = f2bf(v);
                    else                vt[((b * 16 + h) * 64 + dd) * 1024 + i] = f2bf(v);
                }
            }
        }
    } else {
        #pragma unroll
        for (int ni = 0; ni < 4; ++ni) {
            int col = n0 + wn + ni * 16 + l16;
            float bv = bias[col];
            #pragma unroll
            for (int mi = 0; mi < 4; ++mi) {
                #pragma unroll
                for (int r = 0; r < 4; ++r) {
                    int m = m0 + wm + mi * 16 + quad * 4 + r;
                    out[m * 1024 + col] = acc[mi][ni][r] + bv;
                }
            }
        }
    }
}

// ---------------- Flash attention: dbuf K/V, 1 barrier/jt, register P (R9) ----------------
__global__ __launch_bounds__(256) void attn_kernel(const short* __restrict__ q,
                                                   const short* __restrict__ k,
                                                   const short* __restrict__ vt,
                                                   short* __restrict__ ao) {
    __shared__ alignas(16) short Ks[2][64][72];
    __shared__ alignas(16) short Vs[2][64][72];

    const int bh = blockIdx.y, qt = blockIdx.x;
    const int t = threadIdx.x, w = t >> 6, lane = t & 63, quad = lane >> 4, l16 = lane & 15;
    const short* qg = q  + (bh * 1024 + qt * 128) * 64;
    const short* kg = k  + bh * 65536;
    const short* vg = vt + bh * 65536;

    bf16x8 qf[2][2];
    for (int mi = 0; mi < 2; ++mi) {
        const short* qr = qg + (w * 32 + mi * 16 + l16) * 64;
        qf[mi][0] = *(const bf16x8*)(qr + quad * 8);
        qf[mi][1] = *(const bf16x8*)(qr + 32 + quad * 8);
    }

    const int r0 = t >> 3,          c80 = (t & 7) * 8;
    const int r1 = (t + 256) >> 3,  c81 = c80;

    float rs[2] = {0.f, 0.f};
    f32x4 oaccT[2][4];
    for (int mi = 0; mi < 2; ++mi)
        for (int dt = 0; dt < 4; ++dt) oaccT[mi][dt] = (f32x4){0.f, 0.f, 0.f, 0.f};

    {
        float4 a = *(const float4*)&kg[r0 * 64 + c80];
        float4 b = *(const float4*)&kg[r1 * 64 + c81];
        float4 c = *(const float4*)&vg[r0 * 1024 + c80];
        float4 d = *(const float4*)&vg[r1 * 1024 + c81];
        *(float4*)&Ks[0][r0][c80] = a;  *(float4*)&Ks[0][r1][c81] = b;
        *(float4*)&Vs[0][r0][c80] = c;  *(float4*)&Vs[0][r1][c81] = d;
    }

    for (int jt = 0; jt < 16; ++jt) {
        const int cur = jt & 1;
        asm volatile("s_waitcnt lgkmcnt(0)" ::: "memory");
        asm volatile("s_barrier" ::: "memory");

        float4 kr0, kr1, vr0, vr1;
        if (jt < 15) {
            int jn = jt + 1;
            kr0 = *(const float4*)&kg[(jn * 64 + r0) * 64 + c80];
            kr1 = *(const float4*)&kg[(jn * 64 + r1) * 64 + c81];
            vr0 = *(const float4*)&vg[r0 * 1024 + jn * 64 + c80];
            vr1 = *(const float4*)&vg[r1 * 1024 + jn * 64 + c81];
        }

        for (int js = 0; js < 4; ++js) {
            bf16x8 kf0 = *(const bf16x8*)&Ks[cur][js * 16 + l16][quad * 8];
            bf16x8 kf1 = *(const bf16x8*)&Ks[cur][js * 16 + l16][32 + quad * 8];
            bf16x4 vtf[4];
            for (int dt = 0; dt < 4; ++dt)
                vtf[dt] = *(const bf16x4*)&Vs[cur][dt * 16 + l16][js * 16 + quad * 4];
            for (int mi = 0; mi < 2; ++mi) {
                f32x4 s = (f32x4){0.f, 0.f, 0.f, 0.f};
                s = __builtin_amdgcn_mfma_f32_16x16x32_bf16(kf0, qf[mi][0], s, 0, 0, 0);
                s = __builtin_amdgcn_mfma_f32_16x16x32_bf16(kf1, qf[mi][1], s, 0, 0, 0);
                bf16x4 pfrag;
                for (int r = 0; r < 4; ++r) {
                    float p = __builtin_amdgcn_exp2f(s[r]);
                    rs[mi] += p;
                    pfrag[r] = f2bf(p);
                }
                for (int dt = 0; dt < 4; ++dt)
                    oaccT[mi][dt] = __builtin_amdgcn_mfma_f32_16x16x16bf16_1k(
                        vtf[dt], pfrag, oaccT[mi][dt], 0, 0, 0);
            }
        }

        if (jt < 15) {
            const int nxt = cur ^ 1;
            *(float4*)&Ks[nxt][r0][c80] = kr0;  *(float4*)&Ks[nxt][r1][c81] = kr1;
            *(float4*)&Vs[nxt][r0][c80] = vr0;  *(float4*)&Vs[nxt][r1][c81] = vr1;
        }
    }

    for (int mi = 0; mi < 2; ++mi) {
        rs[mi] += __shfl_xor(rs[mi], 16, 64);
        rs[mi] += __shfl_xor(rs[mi], 32, 64);
    }

    const int b = bh >> 4, h = bh & 15;
    for (int mi = 0; mi < 2; ++mi) {
        float inv = 1.0f / rs[mi];
        int i = qt * 128 + w * 32 + mi * 16 + l16;
        short* aor = ao + (b * 1024 + i) * 1024 + h * 64;
        for (int dt = 0; dt < 4; ++dt) {
            bf16x4 o4;
            for (int r = 0; r < 4; ++r) o4[r] = f2bf(oaccT[mi][dt][r] * inv);
            *(bf16x4*)(aor + dt * 16 + quad * 4) = o4;
        }
    }
}

extern "C" void kernel_launch(void* const* d_in, const int* in_sizes, int n_in,
                              void* d_out, int out_size, void* d_ws, size_t ws_size,
                              hipStream_t stream) {
    const float* x      = (const float*)d_in[0];
    const float* w_qkv  = (const float*)d_in[1];
    const float* w_proj = (const float*)d_in[2];
    const float* b_proj = (const float*)d_in[3];
    float* out = (float*)d_out;

    char* ws = (char*)d_ws;
    short* xb     = (short*)(ws);
    short* wqkvb  = (short*)(ws + 16777216);
    short* wprojb = (short*)(ws + 23068672);
    short* qb     = (short*)(ws + 25165824);
    short* kb     = (short*)(ws + 41943040);
    short* vtb    = (short*)(ws + 58720256);
    short* aob    = (short*)(ws + 75497472);

    convert_all<<<12288, 256, 0, stream>>>(x, w_qkv, w_proj, xb, wqkvb, wprojb);
    // QKV: M=8192,N=3072 -> 64x24 tiles of 128x128 = 1536 blocks (2 rounds @3/CU)
    gemm97<0, 24><<<1536, 256, 0, stream>>>(xb, wqkvb, qb, kb, vtb, nullptr, nullptr);
    attn_kernel<<<dim3(8, 128), 256, 0, stream>>>(qb, kb, vtb, aob);
    // proj: M=8192,N=1024 -> 64x8 tiles of 128x128 = 512 blocks (all resident)
    gemm97<1, 8><<<512, 256, 0, stream>>>(aob, wprojb, nullptr, nullptr, nullptr, b_proj, out);
}